// Round 20
// baseline (1148.558 us; speedup 1.0000x reference)
//
#include <hip/hip_runtime.h>
#include <hip/hip_bf16.h>

// FlowNetC correlation via bf16 MFMA Gram (16 tiles/parity).
// out[b, dyi*21+j, y, x] = (1/256) * sum_c in1[b,c,y,x] * in2[b,c,y2,x+2j-20], y2=y+2dyi-20.
// Round-20 fix: single-buffer LDS (16KB) + __launch_bounds__(256,7). r19 showed all
// pipes ~35% at Occupancy 31% (10 waves/CU) with near-minimal FETCH -> latency-bound
// at low occupancy. 16KB LDS + VGPR<=73 allows ~7 blocks/CU (28 waves). Single-buffer
// is race-free: write -> barrier -> compute -> barrier (WAR/RAW both barrier-protected);
// global prefetch->regs still crosses barriers (keep-alive pins pack+vmcnt at writeout).

typedef __attribute__((ext_vector_type(8))) short bf16x8;
typedef __attribute__((ext_vector_type(4))) float f32x4;
typedef __attribute__((ext_vector_type(4))) unsigned u32x4;

constexpr int Bn = 8, Cn = 256, Hn = 96, Wn = 128, GW = 21;
constexpr int KC = 32, NCH = Cn / KC;     // 8 chunks of 32 channels
constexpr int NWG = Bn * Hn * GW;         // 16128, divisible by 8
constexpr int JW = 23;                    // sout pad

__device__ inline unsigned pack_bf16(float lo, float hi) {
    __hip_bfloat16 l = __float2bfloat16(lo);
    __hip_bfloat16 h = __float2bfloat16(hi);
    unsigned short lu, hu;
    __builtin_memcpy(&lu, &l, 2);
    __builtin_memcpy(&hu, &h, 2);
    return (unsigned)lu | ((unsigned)hu << 16);
}

// LDS-visibility barrier WITHOUT the vmcnt(0) drain of __syncthreads() (rule #18).
__device__ inline void lds_barrier() {
    asm volatile("s_waitcnt lgkmcnt(0)" ::: "memory");
    __builtin_amdgcn_s_barrier();
    __builtin_amdgcn_sched_barrier(0);
}

__global__ __launch_bounds__(256, 7) void corr_mfma(
    const float* __restrict__ in1, const float* __restrict__ in2,
    float* __restrict__ out)
{
    // single-buffer: 4 panels [Ae,Ao,Be,Bo][1024 u32] = 16 KB; panel=[mt4][kg4][pos16][ku4]
    // Epilogue overlays sout[128][JW] floats (2944 <= 4096 dwords).
    __shared__ unsigned lds[4][1024];

    // ---- L2-locality decode (r19): XCD owns y-band of 12; (b, par, sub, dyi, yw)
    int orig = blockIdx.x;
    int xcd  = orig & 7;
    int i    = orig >> 3;            // 0..2015
    int yw   = i % 3;  int t = i / 3;
    int dyi  = t % 21; t /= 21;      // t in [0,32)
    int sub  = t & 1;
    int par  = (t >> 1) & 1;
    int b    = t >> 2;               // 0..7
    int y    = 12 * xcd + par + 2 * (3 * sub + yw);

    int y2  = y + 2 * dyi - 20;
    bool y2ok = (y2 >= 0) && (y2 < Hn);

    int tid = threadIdx.x;
    int w   = tid >> 6;          // wave 0..3
    int l   = tid & 63;
    int p   = w >> 1;            // parity
    int h   = w & 1;             // x-half: mt in {2h, 2h+1}
    int g   = l >> 4;            // k-group
    int m16 = l & 15;

    const size_t chw = (size_t)Hn * Wn;
    const float* pA = in1 + ((size_t)b * Cn) * chw + (size_t)y * Wn;
    const float* pB = in2 + ((size_t)b * Cn) * chw + (size_t)(y2ok ? y2 : 0) * Wn;

    // staging task: thread = (tm = x-pair 0..63, tg = kg 0..3); owns channels 8tg..8tg+7
    int tm = tid & 63;
    int tg = tid >> 6;
    const int loff = ((tm >> 4) * 4 + tg) * 64 + (tm & 15) * 4;   // b128-aligned

    f32x4 acc[2][4] = {};        // acc[a][n] = tile (mt=2h+a, nt=n)

    // raw load values as scalar floats (single prefetch set)
    float ax[8], ay[8], bx[8], by[8];

    auto prefetch = [&](int chunk) {
        size_t base = (size_t)(chunk * KC + 8 * tg) * chw + 2 * tm;
#pragma unroll
        for (int k = 0; k < 8; ++k) {
            float2 tA = *(const float2*)(pA + base + (size_t)k * chw);
            float2 tB = *(const float2*)(pB + base + (size_t)k * chw);
            ax[k] = tA.x; ay[k] = tA.y;
            bx[k] = tB.x; by[k] = tB.y;
        }
        __builtin_amdgcn_sched_barrier(0);   // pin issue point: loads go out here
    };

    auto writeout = [&]() {
        // keep-alive: packs (and the counted vmcnt wait) stay HERE, not at load site
#pragma unroll
        for (int k = 0; k < 8; ++k)
            asm volatile("" : "+v"(ax[k]), "+v"(ay[k]), "+v"(bx[k]), "+v"(by[k]));
        u32x4 ae, ao, be, bo;
#pragma unroll
        for (int ku = 0; ku < 4; ++ku) {
            ae[ku] = pack_bf16(ax[2 * ku], ax[2 * ku + 1]);
            ao[ku] = pack_bf16(ay[2 * ku], ay[2 * ku + 1]);
            be[ku] = pack_bf16(bx[2 * ku], bx[2 * ku + 1]);
            bo[ku] = pack_bf16(by[2 * ku], by[2 * ku + 1]);
        }
        *(u32x4*)&lds[0][loff] = ae;
        *(u32x4*)&lds[1][loff] = ao;
        *(u32x4*)&lds[2][loff] = be;
        *(u32x4*)&lds[3][loff] = bo;
    };

    auto compute = [&]() {
        const unsigned* Pa = &lds[p][0];
        const unsigned* Pb = &lds[2 + p][0];
        int fo = g * 64 + m16 * 4;
        bf16x8 A0  = *(const bf16x8*)(Pa + (2 * h + 0) * 256 + fo);
        bf16x8 A1  = *(const bf16x8*)(Pa + (2 * h + 1) * 256 + fo);
        bf16x8 Bf0 = *(const bf16x8*)(Pb + 0 * 256 + fo);
        bf16x8 Bf1 = *(const bf16x8*)(Pb + 1 * 256 + fo);
        bf16x8 Bf2 = *(const bf16x8*)(Pb + 2 * 256 + fo);
        bf16x8 Bf3 = *(const bf16x8*)(Pb + 3 * 256 + fo);
        acc[0][0] = __builtin_amdgcn_mfma_f32_16x16x32_bf16(A0, Bf0, acc[0][0], 0, 0, 0);
        acc[0][1] = __builtin_amdgcn_mfma_f32_16x16x32_bf16(A0, Bf1, acc[0][1], 0, 0, 0);
        acc[0][2] = __builtin_amdgcn_mfma_f32_16x16x32_bf16(A0, Bf2, acc[0][2], 0, 0, 0);
        acc[0][3] = __builtin_amdgcn_mfma_f32_16x16x32_bf16(A0, Bf3, acc[0][3], 0, 0, 0);
        acc[1][0] = __builtin_amdgcn_mfma_f32_16x16x32_bf16(A1, Bf0, acc[1][0], 0, 0, 0);
        acc[1][1] = __builtin_amdgcn_mfma_f32_16x16x32_bf16(A1, Bf1, acc[1][1], 0, 0, 0);
        acc[1][2] = __builtin_amdgcn_mfma_f32_16x16x32_bf16(A1, Bf2, acc[1][2], 0, 0, 0);
        acc[1][3] = __builtin_amdgcn_mfma_f32_16x16x32_bf16(A1, Bf3, acc[1][3], 0, 0, 0);
    };

    if (y2ok) {
        prefetch(0);
        for (int it = 0; it < NCH; ++it) {
            writeout();                    // stage chunk `it` (regs loaded last iter)
            lds_barrier();                 // writes visible to all waves (RAW)
            if (it + 1 < NCH) prefetch(it + 1);   // loads in flight under compute
            compute();
            lds_barrier();                 // all reads done before next writeout (WAR)
        }
    }

    // ---- epilogue: LDS-transposed, coalesced stores ----
    __syncthreads();                       // reuse LDS
    float* sout = (float*)&lds[0][0];      // sout[x][JW], x in [0,128), j in [0,21)

    for (int i2 = tid; i2 < Wn * JW; i2 += 256) sout[i2] = 0.0f;
    __syncthreads();                       // zeros visible

    if (y2ok) {
        const float scale = 1.0f / 256.0f;
#pragma unroll
        for (int a = 0; a < 2; ++a)
#pragma unroll
            for (int n = 0; n < 4; ++n)
#pragma unroll
                for (int r = 0; r < 4; ++r) {
                    int xp = (2 * h + a) * 16 + g * 4 + r;   // x' (C/D row)
                    int up = n * 16 + m16;                   // u' (C/D col)
                    int j  = up - xp + 10;
                    if ((unsigned)j < 21u)
                        sout[(2 * xp + p) * JW + j] = acc[a][n][r] * scale;
                }
    }
    __syncthreads();                       // scatter visible

    unsigned base0 = (unsigned)(((b * (GW * GW) + dyi * GW) * Hn + y) * Wn);
    constexpr unsigned PLANE = (unsigned)(Hn * Wn);
    for (int s = tid; s < GW * Wn; s += 256) {
        int j = s >> 7;                    // s / 128
        int x = s & 127;
        out[base0 + (unsigned)j * PLANE + (unsigned)x] = sout[x * JW + j];
    }
}

extern "C" void kernel_launch(void* const* d_in, const int* in_sizes, int n_in,
                              void* d_out, int out_size, void* d_ws, size_t ws_size,
                              hipStream_t stream) {
    const float* in1 = (const float*)d_in[0];
    const float* in2 = (const float*)d_in[1];
    float* out = (float*)d_out;
    corr_mfma<<<NWG, 256, 0, stream>>>(in1, in2, out);
}

// Round 21
// 283.997 us; speedup vs baseline: 4.0443x; 4.0443x over previous
//
#include <hip/hip_runtime.h>
#include <hip/hip_bf16.h>

// FlowNetC correlation via bf16 MFMA Gram (16 tiles/parity).
// out[b, dyi*21+j, y, x] = (1/256) * sum_c in1[b,c,y,x] * in2[b,c,y2,x+2j-20], y2=y+2dyi-20.
// Round-21 fix: r20's __launch_bounds__(256,7) capped VGPR at ~73 -> compiler spilled
// the accumulator to scratch (VGPR 36, WRITE 169MB->2.57GB, dur 335->1180us). Keep
// r20's single-buffer 16KB LDS (occupancy 31->73% confirmed) but PLAIN launch_bounds:
// natural ~72 VGPR, no spills, LDS allows up to 10 blocks/CU.

typedef __attribute__((ext_vector_type(8))) short bf16x8;
typedef __attribute__((ext_vector_type(4))) float f32x4;
typedef __attribute__((ext_vector_type(4))) unsigned u32x4;

constexpr int Bn = 8, Cn = 256, Hn = 96, Wn = 128, GW = 21;
constexpr int KC = 32, NCH = Cn / KC;     // 8 chunks of 32 channels
constexpr int NWG = Bn * Hn * GW;         // 16128, divisible by 8
constexpr int JW = 23;                    // sout pad

__device__ inline unsigned pack_bf16(float lo, float hi) {
    __hip_bfloat16 l = __float2bfloat16(lo);
    __hip_bfloat16 h = __float2bfloat16(hi);
    unsigned short lu, hu;
    __builtin_memcpy(&lu, &l, 2);
    __builtin_memcpy(&hu, &h, 2);
    return (unsigned)lu | ((unsigned)hu << 16);
}

// LDS-visibility barrier WITHOUT the vmcnt(0) drain of __syncthreads() (rule #18).
__device__ inline void lds_barrier() {
    asm volatile("s_waitcnt lgkmcnt(0)" ::: "memory");
    __builtin_amdgcn_s_barrier();
    __builtin_amdgcn_sched_barrier(0);
}

__global__ __launch_bounds__(256) void corr_mfma(
    const float* __restrict__ in1, const float* __restrict__ in2,
    float* __restrict__ out)
{
    // single-buffer: 4 panels [Ae,Ao,Be,Bo][1024 u32] = 16 KB; panel=[mt4][kg4][pos16][ku4]
    // Epilogue overlays sout[128][JW] floats (2944 <= 4096 dwords).
    __shared__ unsigned lds[4][1024];

    // ---- L2-locality decode (r19): XCD owns y-band of 12; (b, par, sub, dyi, yw)
    int orig = blockIdx.x;
    int xcd  = orig & 7;
    int i    = orig >> 3;            // 0..2015
    int yw   = i % 3;  int t = i / 3;
    int dyi  = t % 21; t /= 21;      // t in [0,32)
    int sub  = t & 1;
    int par  = (t >> 1) & 1;
    int b    = t >> 2;               // 0..7
    int y    = 12 * xcd + par + 2 * (3 * sub + yw);

    int y2  = y + 2 * dyi - 20;
    bool y2ok = (y2 >= 0) && (y2 < Hn);

    int tid = threadIdx.x;
    int w   = tid >> 6;          // wave 0..3
    int l   = tid & 63;
    int p   = w >> 1;            // parity
    int h   = w & 1;             // x-half: mt in {2h, 2h+1}
    int g   = l >> 4;            // k-group
    int m16 = l & 15;

    const size_t chw = (size_t)Hn * Wn;
    const float* pA = in1 + ((size_t)b * Cn) * chw + (size_t)y * Wn;
    const float* pB = in2 + ((size_t)b * Cn) * chw + (size_t)(y2ok ? y2 : 0) * Wn;

    // staging task: thread = (tm = x-pair 0..63, tg = kg 0..3); owns channels 8tg..8tg+7
    int tm = tid & 63;
    int tg = tid >> 6;
    const int loff = ((tm >> 4) * 4 + tg) * 64 + (tm & 15) * 4;   // b128-aligned

    f32x4 acc[2][4] = {};        // acc[a][n] = tile (mt=2h+a, nt=n)

    // raw load values as scalar floats (single prefetch set)
    float ax[8], ay[8], bx[8], by[8];

    auto prefetch = [&](int chunk) {
        size_t base = (size_t)(chunk * KC + 8 * tg) * chw + 2 * tm;
#pragma unroll
        for (int k = 0; k < 8; ++k) {
            float2 tA = *(const float2*)(pA + base + (size_t)k * chw);
            float2 tB = *(const float2*)(pB + base + (size_t)k * chw);
            ax[k] = tA.x; ay[k] = tA.y;
            bx[k] = tB.x; by[k] = tB.y;
        }
        __builtin_amdgcn_sched_barrier(0);   // pin issue point: loads go out here
    };

    auto writeout = [&]() {
        // keep-alive: packs (and the counted vmcnt wait) stay HERE, not at load site
#pragma unroll
        for (int k = 0; k < 8; ++k)
            asm volatile("" : "+v"(ax[k]), "+v"(ay[k]), "+v"(bx[k]), "+v"(by[k]));
        u32x4 ae, ao, be, bo;
#pragma unroll
        for (int ku = 0; ku < 4; ++ku) {
            ae[ku] = pack_bf16(ax[2 * ku], ax[2 * ku + 1]);
            ao[ku] = pack_bf16(ay[2 * ku], ay[2 * ku + 1]);
            be[ku] = pack_bf16(bx[2 * ku], bx[2 * ku + 1]);
            bo[ku] = pack_bf16(by[2 * ku], by[2 * ku + 1]);
        }
        *(u32x4*)&lds[0][loff] = ae;
        *(u32x4*)&lds[1][loff] = ao;
        *(u32x4*)&lds[2][loff] = be;
        *(u32x4*)&lds[3][loff] = bo;
    };

    auto compute = [&]() {
        const unsigned* Pa = &lds[p][0];
        const unsigned* Pb = &lds[2 + p][0];
        int fo = g * 64 + m16 * 4;
        bf16x8 A0  = *(const bf16x8*)(Pa + (2 * h + 0) * 256 + fo);
        bf16x8 A1  = *(const bf16x8*)(Pa + (2 * h + 1) * 256 + fo);
        bf16x8 Bf0 = *(const bf16x8*)(Pb + 0 * 256 + fo);
        bf16x8 Bf1 = *(const bf16x8*)(Pb + 1 * 256 + fo);
        bf16x8 Bf2 = *(const bf16x8*)(Pb + 2 * 256 + fo);
        bf16x8 Bf3 = *(const bf16x8*)(Pb + 3 * 256 + fo);
        acc[0][0] = __builtin_amdgcn_mfma_f32_16x16x32_bf16(A0, Bf0, acc[0][0], 0, 0, 0);
        acc[0][1] = __builtin_amdgcn_mfma_f32_16x16x32_bf16(A0, Bf1, acc[0][1], 0, 0, 0);
        acc[0][2] = __builtin_amdgcn_mfma_f32_16x16x32_bf16(A0, Bf2, acc[0][2], 0, 0, 0);
        acc[0][3] = __builtin_amdgcn_mfma_f32_16x16x32_bf16(A0, Bf3, acc[0][3], 0, 0, 0);
        acc[1][0] = __builtin_amdgcn_mfma_f32_16x16x32_bf16(A1, Bf0, acc[1][0], 0, 0, 0);
        acc[1][1] = __builtin_amdgcn_mfma_f32_16x16x32_bf16(A1, Bf1, acc[1][1], 0, 0, 0);
        acc[1][2] = __builtin_amdgcn_mfma_f32_16x16x32_bf16(A1, Bf2, acc[1][2], 0, 0, 0);
        acc[1][3] = __builtin_amdgcn_mfma_f32_16x16x32_bf16(A1, Bf3, acc[1][3], 0, 0, 0);
    };

    if (y2ok) {
        prefetch(0);
        for (int it = 0; it < NCH; ++it) {
            writeout();                    // stage chunk `it` (regs loaded last iter)
            lds_barrier();                 // writes visible to all waves (RAW)
            if (it + 1 < NCH) prefetch(it + 1);   // loads in flight under compute
            compute();
            lds_barrier();                 // all reads done before next writeout (WAR)
        }
    }

    // ---- epilogue: LDS-transposed, coalesced stores ----
    __syncthreads();                       // reuse LDS
    float* sout = (float*)&lds[0][0];      // sout[x][JW], x in [0,128), j in [0,21)

    for (int i2 = tid; i2 < Wn * JW; i2 += 256) sout[i2] = 0.0f;
    __syncthreads();                       // zeros visible

    if (y2ok) {
        const float scale = 1.0f / 256.0f;
#pragma unroll
        for (int a = 0; a < 2; ++a)
#pragma unroll
            for (int n = 0; n < 4; ++n)
#pragma unroll
                for (int r = 0; r < 4; ++r) {
                    int xp = (2 * h + a) * 16 + g * 4 + r;   // x' (C/D row)
                    int up = n * 16 + m16;                   // u' (C/D col)
                    int j  = up - xp + 10;
                    if ((unsigned)j < 21u)
                        sout[(2 * xp + p) * JW + j] = acc[a][n][r] * scale;
                }
    }
    __syncthreads();                       // scatter visible

    unsigned base0 = (unsigned)(((b * (GW * GW) + dyi * GW) * Hn + y) * Wn);
    constexpr unsigned PLANE = (unsigned)(Hn * Wn);
    for (int s = tid; s < GW * Wn; s += 256) {
        int j = s >> 7;                    // s / 128
        int x = s & 127;
        out[base0 + (unsigned)j * PLANE + (unsigned)x] = sout[x * JW + j];
    }
}

extern "C" void kernel_launch(void* const* d_in, const int* in_sizes, int n_in,
                              void* d_out, int out_size, void* d_ws, size_t ws_size,
                              hipStream_t stream) {
    const float* in1 = (const float*)d_in[0];
    const float* in2 = (const float*)d_in[1];
    float* out = (float*)d_out;
    corr_mfma<<<NWG, 256, 0, stream>>>(in1, in2, out);
}

// Round 22
// 282.910 us; speedup vs baseline: 4.0598x; 1.0038x over previous
//
#include <hip/hip_runtime.h>
#include <hip/hip_bf16.h>

// FlowNetC correlation via bf16 MFMA Gram — 3 dyi per block (21 = 3*7).
// out[b, dyi*21+j, y, x] = (1/256) * sum_c in1[b,c,y,x] * in2[b,c,y2,x+2j-20], y2=y+2dyi-20.
// Round-22: r19-r21 showed traffic/occupancy/prefetch-depth all flat at ~330us with
// every pipe at ~35-40% -> the per-chunk phase machinery (2 barriers + thin compute)
// is the binder. Merging 3 dyi: A staged once (VMEM/pack/LDS-write x2/3 per output),
// barriers x1/3 per output, 72 MFMA per chunk (compute finally covers load latency).

typedef __attribute__((ext_vector_type(8))) short bf16x8;
typedef __attribute__((ext_vector_type(4))) float f32x4;
typedef __attribute__((ext_vector_type(4))) unsigned u32x4;

constexpr int Bn = 8, Cn = 256, Hn = 96, Wn = 128, GW = 21;
constexpr int KC = 32, NCH = Cn / KC;     // 8 chunks of 32 channels
constexpr int NDG = 7;                    // dyi triples
constexpr int NWG = Bn * Hn * NDG;        // 5376, divisible by 8
constexpr int JW = 23;                    // sout pad

__device__ inline unsigned pack_bf16(float lo, float hi) {
    __hip_bfloat16 l = __float2bfloat16(lo);
    __hip_bfloat16 h = __float2bfloat16(hi);
    unsigned short lu, hu;
    __builtin_memcpy(&lu, &l, 2);
    __builtin_memcpy(&hu, &h, 2);
    return (unsigned)lu | ((unsigned)hu << 16);
}

// LDS-visibility barrier WITHOUT the vmcnt(0) drain of __syncthreads() (rule #18).
__device__ inline void lds_barrier() {
    asm volatile("s_waitcnt lgkmcnt(0)" ::: "memory");
    __builtin_amdgcn_s_barrier();
    __builtin_amdgcn_sched_barrier(0);
}

__global__ __launch_bounds__(256) void corr_mfma(
    const float* __restrict__ in1, const float* __restrict__ in2,
    float* __restrict__ out)
{
    // 8 panels [Ae,Ao,B0e,B0o,B1e,B1o,B2e,B2o][1024 u32] = 32 KB single-buffer.
    // panel = [mt4][kg4][pos16][ku4] of bf16x2. Epilogue overlays sout (2944 f32).
    __shared__ unsigned lds[8][1024];

    // ---- L2-locality decode: XCD owns y-band of 12; (b, par, sub, dg, yw)
    int orig = blockIdx.x;
    int xcd  = orig & 7;
    int i    = orig >> 3;            // 0..671
    int yw   = i % 3;  int t = i / 3;
    int dg   = t % NDG; t /= NDG;    // t in [0,32)
    int sub  = t & 1;
    int par  = (t >> 1) & 1;
    int b    = t >> 2;               // 0..7
    int y    = 12 * xcd + par + 2 * (3 * sub + yw);

    int rowv[3], y2c[3];
#pragma unroll
    for (int d = 0; d < 3; ++d) {
        int y2 = y + 2 * (3 * dg + d) - 20;
        rowv[d] = (y2 >= 0) && (y2 < Hn);
        y2c[d]  = rowv[d] ? y2 : 0;
    }
    bool anyv = rowv[0] || rowv[1] || rowv[2];

    int tid = threadIdx.x;
    int w   = tid >> 6;          // wave 0..3
    int l   = tid & 63;
    int p   = w >> 1;            // parity
    int h   = w & 1;             // x-half: mt in {2h, 2h+1}
    int g   = l >> 4;            // k-group
    int m16 = l & 15;

    const size_t chw = (size_t)Hn * Wn;
    const size_t bb  = (size_t)b * Cn * chw;
    const float* pA  = in1 + bb + (size_t)y * Wn;
    const float* pB0 = in2 + bb + (size_t)y2c[0] * Wn;
    const float* pB1 = in2 + bb + (size_t)y2c[1] * Wn;
    const float* pB2 = in2 + bb + (size_t)y2c[2] * Wn;

    // staging task: thread = (tm = x-pair 0..63, tg = kg 0..3); owns channels 8tg..8tg+7
    int tm = tid & 63;
    int tg = tid >> 6;
    const int loff = ((tm >> 4) * 4 + tg) * 64 + (tm & 15) * 4;   // b128-aligned

    f32x4 acc[3][2][4] = {};     // acc[d][a][n]; all indices compile-time after unroll

    // raw load values (single prefetch set): 64 floats
    float ax[8], ay[8], b0x[8], b0y[8], b1x[8], b1y[8], b2x[8], b2y[8];

    auto prefetch = [&](int chunk) {
        size_t base = (size_t)(chunk * KC + 8 * tg) * chw + 2 * tm;
#pragma unroll
        for (int k = 0; k < 8; ++k) {
            float2 tA = *(const float2*)(pA  + base + (size_t)k * chw);
            float2 t0 = *(const float2*)(pB0 + base + (size_t)k * chw);
            float2 t1 = *(const float2*)(pB1 + base + (size_t)k * chw);
            float2 t2 = *(const float2*)(pB2 + base + (size_t)k * chw);
            ax[k] = tA.x; ay[k] = tA.y;
            b0x[k] = t0.x; b0y[k] = t0.y;
            b1x[k] = t1.x; b1y[k] = t1.y;
            b2x[k] = t2.x; b2y[k] = t2.y;
        }
        __builtin_amdgcn_sched_barrier(0);   // pin issue point
    };

    auto writeout = [&]() {
#pragma unroll
        for (int k = 0; k < 8; ++k) {
            asm volatile("" : "+v"(ax[k]), "+v"(ay[k]), "+v"(b0x[k]), "+v"(b0y[k]));
            asm volatile("" : "+v"(b1x[k]), "+v"(b1y[k]), "+v"(b2x[k]), "+v"(b2y[k]));
        }
        u32x4 ae, ao, e0, o0, e1, o1, e2, o2;
#pragma unroll
        for (int ku = 0; ku < 4; ++ku) {
            ae[ku] = pack_bf16(ax[2 * ku], ax[2 * ku + 1]);
            ao[ku] = pack_bf16(ay[2 * ku], ay[2 * ku + 1]);
            e0[ku] = pack_bf16(b0x[2 * ku], b0x[2 * ku + 1]);
            o0[ku] = pack_bf16(b0y[2 * ku], b0y[2 * ku + 1]);
            e1[ku] = pack_bf16(b1x[2 * ku], b1x[2 * ku + 1]);
            o1[ku] = pack_bf16(b1y[2 * ku], b1y[2 * ku + 1]);
            e2[ku] = pack_bf16(b2x[2 * ku], b2x[2 * ku + 1]);
            o2[ku] = pack_bf16(b2y[2 * ku], b2y[2 * ku + 1]);
        }
        // zero-mask invalid dyi slots (uniform scalar branch per slot)
        if (!rowv[0]) { e0 = (u32x4)(0u); o0 = (u32x4)(0u); }
        if (!rowv[1]) { e1 = (u32x4)(0u); o1 = (u32x4)(0u); }
        if (!rowv[2]) { e2 = (u32x4)(0u); o2 = (u32x4)(0u); }
        *(u32x4*)&lds[0][loff] = ae;
        *(u32x4*)&lds[1][loff] = ao;
        *(u32x4*)&lds[2][loff] = e0;
        *(u32x4*)&lds[3][loff] = o0;
        *(u32x4*)&lds[4][loff] = e1;
        *(u32x4*)&lds[5][loff] = o1;
        *(u32x4*)&lds[6][loff] = e2;
        *(u32x4*)&lds[7][loff] = o2;
    };

    auto compute = [&]() {
        const unsigned* Pa = &lds[p][0];
        int fo = g * 64 + m16 * 4;
        bf16x8 A0 = *(const bf16x8*)(Pa + (2 * h + 0) * 256 + fo);
        bf16x8 A1 = *(const bf16x8*)(Pa + (2 * h + 1) * 256 + fo);
#pragma unroll
        for (int d = 0; d < 3; ++d) {
            const unsigned* Pb = &lds[2 + 2 * d + p][0];
            bf16x8 Bf0 = *(const bf16x8*)(Pb + 0 * 256 + fo);
            bf16x8 Bf1 = *(const bf16x8*)(Pb + 1 * 256 + fo);
            bf16x8 Bf2 = *(const bf16x8*)(Pb + 2 * 256 + fo);
            bf16x8 Bf3 = *(const bf16x8*)(Pb + 3 * 256 + fo);
            acc[d][0][0] = __builtin_amdgcn_mfma_f32_16x16x32_bf16(A0, Bf0, acc[d][0][0], 0, 0, 0);
            acc[d][0][1] = __builtin_amdgcn_mfma_f32_16x16x32_bf16(A0, Bf1, acc[d][0][1], 0, 0, 0);
            acc[d][0][2] = __builtin_amdgcn_mfma_f32_16x16x32_bf16(A0, Bf2, acc[d][0][2], 0, 0, 0);
            acc[d][0][3] = __builtin_amdgcn_mfma_f32_16x16x32_bf16(A0, Bf3, acc[d][0][3], 0, 0, 0);
            acc[d][1][0] = __builtin_amdgcn_mfma_f32_16x16x32_bf16(A1, Bf0, acc[d][1][0], 0, 0, 0);
            acc[d][1][1] = __builtin_amdgcn_mfma_f32_16x16x32_bf16(A1, Bf1, acc[d][1][1], 0, 0, 0);
            acc[d][1][2] = __builtin_amdgcn_mfma_f32_16x16x32_bf16(A1, Bf2, acc[d][1][2], 0, 0, 0);
            acc[d][1][3] = __builtin_amdgcn_mfma_f32_16x16x32_bf16(A1, Bf3, acc[d][1][3], 0, 0, 0);
        }
    };

    if (anyv) {
        prefetch(0);
        for (int it = 0; it < NCH; ++it) {
            writeout();                    // stage chunk `it`
            lds_barrier();                 // RAW: writes visible
            if (it + 1 < NCH) prefetch(it + 1);
            compute();
            lds_barrier();                 // WAR: reads drained
        }
    }

    // ---- epilogue: 3 planes, LDS-transposed coalesced stores ----
    float* sout = (float*)&lds[0][0];      // sout[x][JW], 2944 floats
    const float scale = 1.0f / 256.0f;
    constexpr unsigned PLANE = (unsigned)(Hn * Wn);

#pragma unroll
    for (int d = 0; d < 3; ++d) {
        __syncthreads();                   // previous reads/stores done
        for (int i2 = tid; i2 < Wn * JW; i2 += 256) sout[i2] = 0.0f;
        __syncthreads();                   // zeros visible
        if (rowv[d]) {
#pragma unroll
            for (int a = 0; a < 2; ++a)
#pragma unroll
                for (int n = 0; n < 4; ++n)
#pragma unroll
                    for (int r = 0; r < 4; ++r) {
                        int xp = (2 * h + a) * 16 + g * 4 + r;   // x' (C/D row)
                        int up = n * 16 + m16;                   // u' (C/D col)
                        int j  = up - xp + 10;
                        if ((unsigned)j < 21u)
                            sout[(2 * xp + p) * JW + j] = acc[d][a][n][r] * scale;
                    }
        }
        __syncthreads();                   // scatter visible
        unsigned base0 = (unsigned)(((b * (GW * GW) + (3 * dg + d) * GW) * Hn + y) * Wn);
        for (int s = tid; s < GW * Wn; s += 256) {
            int j = s >> 7;
            int x = s & 127;
            out[base0 + (unsigned)j * PLANE + (unsigned)x] = sout[x * JW + j];
        }
    }
}

extern "C" void kernel_launch(void* const* d_in, const int* in_sizes, int n_in,
                              void* d_out, int out_size, void* d_ws, size_t ws_size,
                              hipStream_t stream) {
    const float* in1 = (const float*)d_in[0];
    const float* in2 = (const float*)d_in[1];
    float* out = (float*)d_out;
    corr_mfma<<<NWG, 256, 0, stream>>>(in1, in2, out);
}

// Round 24
// 186.716 us; speedup vs baseline: 6.1514x; 1.5152x over previous
//
#include <hip/hip_runtime.h>
#include <hip/hip_bf16.h>

// FlowNetC correlation, round 24: prepack(f32->bf16 panels) + BARRIER-FREE main.
// out[b, dyi*21+j, y, x] = (1/256) * sum_c in1[b,c,y,x] * in2[b,c,y2,x+2j-20].
// Key insight: with operands pre-packed in MFMA panel layout, each lane's fragment is
// a contiguous 16B global load (wave = one coalesced 1KB panel slice). Main kernel:
// 6 frag loads + 8 MFMAs per chunk per wave, register-pipelined, ZERO barriers, zero
// LDS staging, zero staging VALU -- deletes the phase machinery that r18-r22 showed
// invariant at ~320us. (r23's global_load_lds+counted-vmcnt template raced; dropped.)

typedef __attribute__((ext_vector_type(8))) short bf16x8;
typedef __attribute__((ext_vector_type(4))) float f32x4;
typedef __attribute__((ext_vector_type(4))) unsigned u32x4;

constexpr int Bn = 8, Cn = 256, Hn = 96, Wn = 128, GW = 21;
constexpr int KC = 32, NCH = Cn / KC;     // 8 chunks of 32 channels
constexpr int NWG = Bn * Hn * GW;         // 16128, divisible by 8
constexpr int JW = 23;                    // sout pad
constexpr size_t TELEMS = (size_t)Bn * Hn * NCH * 2048;  // 12,582,912 u32 per input

__device__ inline unsigned pack_bf16(float lo, float hi) {
    __hip_bfloat16 l = __float2bfloat16(lo);
    __hip_bfloat16 h = __float2bfloat16(hi);
    unsigned short lu, hu;
    __builtin_memcpy(&lu, &l, 2);
    __builtin_memcpy(&hu, &h, 2);
    return (unsigned)lu | ((unsigned)hu << 16);
}

// ---------------- prepack: f32 -> bf16-pair u32 panels ----------------
// T[inp][b][y][chunk][par][mt4][kg4][pos16][ku4]; u32 = {bf16(c), bf16(c+1)},
// c = chunk*32 + 8*kg + 2*ku, x = 2*(mt*16+pos)+par. Same staging pattern as the
// proven r21 writeout, done once. Block = (inp,b,y,chunk); thread=(tm,tg).
__global__ __launch_bounds__(256) void prepack(
    const float* __restrict__ in1, const float* __restrict__ in2,
    unsigned* __restrict__ T)
{
    unsigned u = blockIdx.x;
    int ch = u & 7;  u >>= 3;
    int y  = u % 96; u /= 96;
    int b  = u & 7;  u >>= 3;
    const float* src = u ? in2 : in1;

    int t  = threadIdx.x;
    int tm = t & 63;          // x-pair
    int tg = t >> 6;          // kg

    const size_t chw = (size_t)Hn * Wn;
    const float* p = src + ((size_t)(b * Cn + ch * 32 + 8 * tg)) * chw
                         + (size_t)y * Wn + 2 * tm;
    float2 f[8];
#pragma unroll
    for (int k = 0; k < 8; ++k)
        f[k] = *(const float2*)(p + (size_t)k * chw);

    u32x4 ae, ao;
#pragma unroll
    for (int ku = 0; ku < 4; ++ku) {
        ae[ku] = pack_bf16(f[2 * ku].x, f[2 * ku + 1].x);
        ao[ku] = pack_bf16(f[2 * ku].y, f[2 * ku + 1].y);
    }
    unsigned* To = T + u * TELEMS + ((size_t)(b * Hn + y) * NCH + ch) * 2048
                     + ((tm >> 4) * 4 + tg) * 64 + (tm & 15) * 4;
    *(u32x4*)(To)        = ae;    // par 0
    *(u32x4*)(To + 1024) = ao;    // par 1
}

// ---------------- main: barrier-free fragment-direct MFMA Gram ----------------
__global__ __launch_bounds__(256) void corr_frag(
    const unsigned* __restrict__ T1, const unsigned* __restrict__ T2,
    float* __restrict__ out)
{
    __shared__ float sout[Wn * JW];   // 11.5 KB, epilogue only

    // r19 L2-locality decode: XCD owns y-band of 12; (b, par, sub, dyi, yw)
    int orig = blockIdx.x;
    int xcd  = orig & 7;
    int i    = orig >> 3;
    int yw   = i % 3;  int t = i / 3;
    int dyi  = t % 21; t /= 21;
    int sub  = t & 1;
    int par  = (t >> 1) & 1;
    int b    = t >> 2;
    int y    = 12 * xcd + par + 2 * (3 * sub + yw);

    int y2  = y + 2 * dyi - 20;
    bool y2ok = (y2 >= 0) && (y2 < Hn);

    int tid = threadIdx.x;
    int w   = tid >> 6;          // wave 0..3
    int l   = tid & 63;
    int p   = w >> 1;            // parity
    int h   = w & 1;             // x-half: mt in {2h, 2h+1}
    int g   = l >> 4;            // k-group
    int m16 = l & 15;

    f32x4 acc[2][4] = {};        // acc[a][n] = tile (mt=2h+a, nt=n)

    if (y2ok) {
        // per-lane fragment base: panel(par=p) + kg(g)*64 + pos(m16)*4
        const unsigned* pa = T1 + (size_t)(b * Hn + y)  * (NCH * 2048)
                                + p * 1024 + g * 64 + m16 * 4;
        const unsigned* pb = T2 + (size_t)(b * Hn + y2) * (NCH * 2048)
                                + p * 1024 + g * 64 + m16 * 4;

        bf16x8 ca0, ca1, cb0, cb1, cb2, cb3;      // current chunk frags
        ca0 = *(const bf16x8*)(pa + (2 * h + 0) * 256);
        ca1 = *(const bf16x8*)(pa + (2 * h + 1) * 256);
        cb0 = *(const bf16x8*)(pb + 0 * 256);
        cb1 = *(const bf16x8*)(pb + 1 * 256);
        cb2 = *(const bf16x8*)(pb + 2 * 256);
        cb3 = *(const bf16x8*)(pb + 3 * 256);

        for (int ch = 0; ch < NCH; ++ch) {
            bf16x8 na0, na1, nb0, nb1, nb2, nb3;
            if (ch + 1 < NCH) {                   // prefetch next chunk's frags
                const unsigned* A = pa + (ch + 1) * 2048;
                const unsigned* B = pb + (ch + 1) * 2048;
                na0 = *(const bf16x8*)(A + (2 * h + 0) * 256);
                na1 = *(const bf16x8*)(A + (2 * h + 1) * 256);
                nb0 = *(const bf16x8*)(B + 0 * 256);
                nb1 = *(const bf16x8*)(B + 1 * 256);
                nb2 = *(const bf16x8*)(B + 2 * 256);
                nb3 = *(const bf16x8*)(B + 3 * 256);
            }
            acc[0][0] = __builtin_amdgcn_mfma_f32_16x16x32_bf16(ca0, cb0, acc[0][0], 0, 0, 0);
            acc[0][1] = __builtin_amdgcn_mfma_f32_16x16x32_bf16(ca0, cb1, acc[0][1], 0, 0, 0);
            acc[0][2] = __builtin_amdgcn_mfma_f32_16x16x32_bf16(ca0, cb2, acc[0][2], 0, 0, 0);
            acc[0][3] = __builtin_amdgcn_mfma_f32_16x16x32_bf16(ca0, cb3, acc[0][3], 0, 0, 0);
            acc[1][0] = __builtin_amdgcn_mfma_f32_16x16x32_bf16(ca1, cb0, acc[1][0], 0, 0, 0);
            acc[1][1] = __builtin_amdgcn_mfma_f32_16x16x32_bf16(ca1, cb1, acc[1][1], 0, 0, 0);
            acc[1][2] = __builtin_amdgcn_mfma_f32_16x16x32_bf16(ca1, cb2, acc[1][2], 0, 0, 0);
            acc[1][3] = __builtin_amdgcn_mfma_f32_16x16x32_bf16(ca1, cb3, acc[1][3], 0, 0, 0);
            ca0 = na0; ca1 = na1;
            cb0 = nb0; cb1 = nb1; cb2 = nb2; cb3 = nb3;
        }
    }

    // ---- epilogue: LDS-transposed, coalesced stores (r18, proven) ----
    for (int i2 = tid; i2 < Wn * JW; i2 += 256) sout[i2] = 0.0f;
    __syncthreads();                       // zeros visible

    if (y2ok) {
        const float scale = 1.0f / 256.0f;
#pragma unroll
        for (int a = 0; a < 2; ++a)
#pragma unroll
            for (int n = 0; n < 4; ++n)
#pragma unroll
                for (int r = 0; r < 4; ++r) {
                    int xp = (2 * h + a) * 16 + g * 4 + r;   // x' (C/D row)
                    int up = n * 16 + m16;                   // u' (C/D col)
                    int j  = up - xp + 10;
                    if ((unsigned)j < 21u)
                        sout[(2 * xp + p) * JW + j] = acc[a][n][r] * scale;
                }
    }
    __syncthreads();                       // scatter visible

    unsigned base0 = (unsigned)(((b * (GW * GW) + dyi * GW) * Hn + y) * Wn);
    constexpr unsigned PLANE = (unsigned)(Hn * Wn);
    for (int s = tid; s < GW * Wn; s += 256) {
        int j = s >> 7;
        int x = s & 127;
        out[base0 + (unsigned)j * PLANE + (unsigned)x] = sout[x * JW + j];
    }
}

// ---------------- fallback (r21, proven): used if ws too small ----------------
__device__ inline void lds_barrier() {
    asm volatile("s_waitcnt lgkmcnt(0)" ::: "memory");
    __builtin_amdgcn_s_barrier();
    __builtin_amdgcn_sched_barrier(0);
}

__global__ __launch_bounds__(256) void corr_mfma_fb(
    const float* __restrict__ in1, const float* __restrict__ in2,
    float* __restrict__ out)
{
    __shared__ unsigned lds[4][1024];
    int orig = blockIdx.x;
    int xcd  = orig & 7;
    int i    = orig >> 3;
    int yw   = i % 3;  int t = i / 3;
    int dyi  = t % 21; t /= 21;
    int sub  = t & 1;
    int par  = (t >> 1) & 1;
    int b    = t >> 2;
    int y    = 12 * xcd + par + 2 * (3 * sub + yw);
    int y2  = y + 2 * dyi - 20;
    bool y2ok = (y2 >= 0) && (y2 < Hn);

    int tid = threadIdx.x;
    int w   = tid >> 6;
    int l   = tid & 63;
    int p   = w >> 1;
    int h   = w & 1;
    int g   = l >> 4;
    int m16 = l & 15;

    const size_t chw = (size_t)Hn * Wn;
    const float* pA = in1 + ((size_t)b * Cn) * chw + (size_t)y * Wn;
    const float* pB = in2 + ((size_t)b * Cn) * chw + (size_t)(y2ok ? y2 : 0) * Wn;

    int tm = tid & 63;
    int tg = tid >> 6;
    const int loff = ((tm >> 4) * 4 + tg) * 64 + (tm & 15) * 4;

    f32x4 acc[2][4] = {};
    float ax[8], ay[8], bx[8], by[8];

    auto prefetch = [&](int chunk) {
        size_t base = (size_t)(chunk * KC + 8 * tg) * chw + 2 * tm;
#pragma unroll
        for (int k = 0; k < 8; ++k) {
            float2 tA = *(const float2*)(pA + base + (size_t)k * chw);
            float2 tB = *(const float2*)(pB + base + (size_t)k * chw);
            ax[k] = tA.x; ay[k] = tA.y;
            bx[k] = tB.x; by[k] = tB.y;
        }
        __builtin_amdgcn_sched_barrier(0);
    };
    auto writeout = [&]() {
#pragma unroll
        for (int k = 0; k < 8; ++k)
            asm volatile("" : "+v"(ax[k]), "+v"(ay[k]), "+v"(bx[k]), "+v"(by[k]));
        u32x4 ae, ao, be, bo;
#pragma unroll
        for (int ku = 0; ku < 4; ++ku) {
            ae[ku] = pack_bf16(ax[2 * ku], ax[2 * ku + 1]);
            ao[ku] = pack_bf16(ay[2 * ku], ay[2 * ku + 1]);
            be[ku] = pack_bf16(bx[2 * ku], bx[2 * ku + 1]);
            bo[ku] = pack_bf16(by[2 * ku], by[2 * ku + 1]);
        }
        *(u32x4*)&lds[0][loff] = ae;
        *(u32x4*)&lds[1][loff] = ao;
        *(u32x4*)&lds[2][loff] = be;
        *(u32x4*)&lds[3][loff] = bo;
    };
    auto compute = [&]() {
        const unsigned* Pa = &lds[p][0];
        const unsigned* Pb = &lds[2 + p][0];
        int fo = g * 64 + m16 * 4;
        bf16x8 A0  = *(const bf16x8*)(Pa + (2 * h + 0) * 256 + fo);
        bf16x8 A1  = *(const bf16x8*)(Pa + (2 * h + 1) * 256 + fo);
        bf16x8 Bf0 = *(const bf16x8*)(Pb + 0 * 256 + fo);
        bf16x8 Bf1 = *(const bf16x8*)(Pb + 1 * 256 + fo);
        bf16x8 Bf2 = *(const bf16x8*)(Pb + 2 * 256 + fo);
        bf16x8 Bf3 = *(const bf16x8*)(Pb + 3 * 256 + fo);
        acc[0][0] = __builtin_amdgcn_mfma_f32_16x16x32_bf16(A0, Bf0, acc[0][0], 0, 0, 0);
        acc[0][1] = __builtin_amdgcn_mfma_f32_16x16x32_bf16(A0, Bf1, acc[0][1], 0, 0, 0);
        acc[0][2] = __builtin_amdgcn_mfma_f32_16x16x32_bf16(A0, Bf2, acc[0][2], 0, 0, 0);
        acc[0][3] = __builtin_amdgcn_mfma_f32_16x16x32_bf16(A0, Bf3, acc[0][3], 0, 0, 0);
        acc[1][0] = __builtin_amdgcn_mfma_f32_16x16x32_bf16(A1, Bf0, acc[1][0], 0, 0, 0);
        acc[1][1] = __builtin_amdgcn_mfma_f32_16x16x32_bf16(A1, Bf1, acc[1][1], 0, 0, 0);
        acc[1][2] = __builtin_amdgcn_mfma_f32_16x16x32_bf16(A1, Bf2, acc[1][2], 0, 0, 0);
        acc[1][3] = __builtin_amdgcn_mfma_f32_16x16x32_bf16(A1, Bf3, acc[1][3], 0, 0, 0);
    };

    if (y2ok) {
        prefetch(0);
        for (int it = 0; it < NCH; ++it) {
            writeout();
            lds_barrier();
            if (it + 1 < NCH) prefetch(it + 1);
            compute();
            lds_barrier();
        }
    }

    __syncthreads();
    float* sout = (float*)&lds[0][0];
    for (int i2 = tid; i2 < Wn * JW; i2 += 256) sout[i2] = 0.0f;
    __syncthreads();
    if (y2ok) {
        const float scale = 1.0f / 256.0f;
#pragma unroll
        for (int a = 0; a < 2; ++a)
#pragma unroll
            for (int n = 0; n < 4; ++n)
#pragma unroll
                for (int r = 0; r < 4; ++r) {
                    int xp = (2 * h + a) * 16 + g * 4 + r;
                    int up = n * 16 + m16;
                    int j  = up - xp + 10;
                    if ((unsigned)j < 21u)
                        sout[(2 * xp + p) * JW + j] = acc[a][n][r] * scale;
                }
    }
    __syncthreads();
    unsigned base0 = (unsigned)(((b * (GW * GW) + dyi * GW) * Hn + y) * Wn);
    constexpr unsigned PLANE = (unsigned)(Hn * Wn);
    for (int s = tid; s < GW * Wn; s += 256) {
        int j = s >> 7;
        int x = s & 127;
        out[base0 + (unsigned)j * PLANE + (unsigned)x] = sout[x * JW + j];
    }
}

extern "C" void kernel_launch(void* const* d_in, const int* in_sizes, int n_in,
                              void* d_out, int out_size, void* d_ws, size_t ws_size,
                              hipStream_t stream) {
    const float* in1 = (const float*)d_in[0];
    const float* in2 = (const float*)d_in[1];
    float* out = (float*)d_out;
    size_t need = 2 * TELEMS * sizeof(unsigned);   // 100,663,296 B
    if (ws_size >= need) {
        unsigned* T = (unsigned*)d_ws;
        prepack<<<2 * Bn * Hn * NCH, 256, 0, stream>>>(in1, in2, T);
        corr_frag<<<NWG, 256, 0, stream>>>(T, T + TELEMS, out);
    } else {
        corr_mfma_fb<<<NWG, 256, 0, stream>>>(in1, in2, out);
    }
}

// Round 25
// 172.252 us; speedup vs baseline: 6.6679x; 1.0840x over previous
//
#include <hip/hip_runtime.h>
#include <hip/hip_bf16.h>

// FlowNetC correlation, round 25: prepack + barrier-free fragment-direct MFMA,
// BAND-ONLY compute. r24 (all 16 tiles) passed at 187us total, L2-BW-bound
// (192KB/block, ~19 TB/s). Tiles with |nt-mt|>=2 are provably dead: j=up-xp+10
// is outside [0,21) for every lane/reg, so the j-guard epilogue never stores them.
// Skip them: 5 MFMAs (was 8) + 3 B-rows (was 4) per wave per chunk. Epilogue is
// byte-identical to r24 (proven) -- no new mapping surface.

typedef __attribute__((ext_vector_type(8))) short bf16x8;
typedef __attribute__((ext_vector_type(4))) float f32x4;
typedef __attribute__((ext_vector_type(4))) unsigned u32x4;

constexpr int Bn = 8, Cn = 256, Hn = 96, Wn = 128, GW = 21;
constexpr int KC = 32, NCH = Cn / KC;     // 8 chunks of 32 channels
constexpr int NWG = Bn * Hn * GW;         // 16128, divisible by 8
constexpr int JW = 23;                    // sout pad
constexpr size_t TELEMS = (size_t)Bn * Hn * NCH * 2048;  // 12,582,912 u32 per input

__device__ inline unsigned pack_bf16(float lo, float hi) {
    __hip_bfloat16 l = __float2bfloat16(lo);
    __hip_bfloat16 h = __float2bfloat16(hi);
    unsigned short lu, hu;
    __builtin_memcpy(&lu, &l, 2);
    __builtin_memcpy(&hu, &h, 2);
    return (unsigned)lu | ((unsigned)hu << 16);
}

// ---------------- prepack: f32 -> bf16-pair u32 panels (r24, proven) ----------------
// T[inp][b][y][chunk][par][mt4][kg4][pos16][ku4]; u32 = {bf16(c), bf16(c+1)},
// c = chunk*32 + 8*kg + 2*ku, x = 2*(mt*16+pos)+par.
__global__ __launch_bounds__(256) void prepack(
    const float* __restrict__ in1, const float* __restrict__ in2,
    unsigned* __restrict__ T)
{
    unsigned u = blockIdx.x;
    int ch = u & 7;  u >>= 3;
    int y  = u % 96; u /= 96;
    int b  = u & 7;  u >>= 3;
    const float* src = u ? in2 : in1;

    int t  = threadIdx.x;
    int tm = t & 63;          // x-pair
    int tg = t >> 6;          // kg

    const size_t chw = (size_t)Hn * Wn;
    const float* p = src + ((size_t)(b * Cn + ch * 32 + 8 * tg)) * chw
                         + (size_t)y * Wn + 2 * tm;
    float2 f[8];
#pragma unroll
    for (int k = 0; k < 8; ++k)
        f[k] = *(const float2*)(p + (size_t)k * chw);

    u32x4 ae, ao;
#pragma unroll
    for (int ku = 0; ku < 4; ++ku) {
        ae[ku] = pack_bf16(f[2 * ku].x, f[2 * ku + 1].x);
        ao[ku] = pack_bf16(f[2 * ku].y, f[2 * ku + 1].y);
    }
    unsigned* To = T + u * TELEMS + ((size_t)(b * Hn + y) * NCH + ch) * 2048
                     + ((tm >> 4) * 4 + tg) * 64 + (tm & 15) * 4;
    *(u32x4*)(To)        = ae;    // par 0
    *(u32x4*)(To + 1024) = ao;    // par 1
}

// ---------------- main: barrier-free band-only fragment-direct MFMA Gram ----------------
__global__ __launch_bounds__(256) void corr_frag(
    const unsigned* __restrict__ T1, const unsigned* __restrict__ T2,
    float* __restrict__ out)
{
    __shared__ float sout[Wn * JW];   // 11.5 KB, epilogue only

    // r19 L2-locality decode: XCD owns y-band of 12; (b, par, sub, dyi, yw)
    int orig = blockIdx.x;
    int xcd  = orig & 7;
    int i    = orig >> 3;
    int yw   = i % 3;  int t = i / 3;
    int dyi  = t % 21; t /= 21;
    int sub  = t & 1;
    int par  = (t >> 1) & 1;
    int b    = t >> 2;
    int y    = 12 * xcd + par + 2 * (3 * sub + yw);

    int y2  = y + 2 * dyi - 20;
    bool y2ok = (y2 >= 0) && (y2 < Hn);

    int tid = threadIdx.x;
    int w   = tid >> 6;          // wave 0..3
    int l   = tid & 63;
    int p   = w >> 1;            // parity
    int h   = w & 1;             // x-half: mt in {2h, 2h+1}
    int g   = l >> 4;            // k-group
    int m16 = l & 15;

    f32x4 acc[2][4] = {};        // acc[a][n] = tile (mt=2h+a, nt=n); only band entries updated

    if (y2ok) {
        // per-lane fragment base: panel(par=p) + kg(g)*64 + pos(m16)*4
        const unsigned* pa = T1 + (size_t)(b * Hn + y)  * (NCH * 2048)
                                + p * 1024 + g * 64 + m16 * 4;
        // B rows needed: nt = h..h+2 (band |nt-mt|<=1 for mt in {2h,2h+1})
        const unsigned* pb = T2 + (size_t)(b * Hn + y2) * (NCH * 2048)
                                + p * 1024 + g * 64 + m16 * 4 + h * 256;

        bf16x8 ca0, ca1, cb0, cb1, cb2;           // current chunk frags
        ca0 = *(const bf16x8*)(pa + (2 * h + 0) * 256);
        ca1 = *(const bf16x8*)(pa + (2 * h + 1) * 256);
        cb0 = *(const bf16x8*)(pb + 0 * 256);
        cb1 = *(const bf16x8*)(pb + 1 * 256);
        cb2 = *(const bf16x8*)(pb + 2 * 256);

        for (int ch = 0; ch < NCH; ++ch) {
            bf16x8 na0, na1, nb0, nb1, nb2;
            if (ch + 1 < NCH) {                   // prefetch next chunk's frags
                const unsigned* A = pa + (ch + 1) * 2048;
                const unsigned* B = pb + (ch + 1) * 2048;
                na0 = *(const bf16x8*)(A + (2 * h + 0) * 256);
                na1 = *(const bf16x8*)(A + (2 * h + 1) * 256);
                nb0 = *(const bf16x8*)(B + 0 * 256);
                nb1 = *(const bf16x8*)(B + 1 * 256);
                nb2 = *(const bf16x8*)(B + 2 * 256);
            }
            // band tiles only; cb_k holds B row (h+k). Wave-uniform branch on h.
            if (h == 0) {
                // mt=0: nt 0,1; mt=1: nt 0,1,2
                acc[0][0] = __builtin_amdgcn_mfma_f32_16x16x32_bf16(ca0, cb0, acc[0][0], 0, 0, 0);
                acc[0][1] = __builtin_amdgcn_mfma_f32_16x16x32_bf16(ca0, cb1, acc[0][1], 0, 0, 0);
                acc[1][0] = __builtin_amdgcn_mfma_f32_16x16x32_bf16(ca1, cb0, acc[1][0], 0, 0, 0);
                acc[1][1] = __builtin_amdgcn_mfma_f32_16x16x32_bf16(ca1, cb1, acc[1][1], 0, 0, 0);
                acc[1][2] = __builtin_amdgcn_mfma_f32_16x16x32_bf16(ca1, cb2, acc[1][2], 0, 0, 0);
            } else {
                // mt=2: nt 1,2,3 (cb0=row1,cb1=row2,cb2=row3); mt=3: nt 2,3
                acc[0][1] = __builtin_amdgcn_mfma_f32_16x16x32_bf16(ca0, cb0, acc[0][1], 0, 0, 0);
                acc[0][2] = __builtin_amdgcn_mfma_f32_16x16x32_bf16(ca0, cb1, acc[0][2], 0, 0, 0);
                acc[0][3] = __builtin_amdgcn_mfma_f32_16x16x32_bf16(ca0, cb2, acc[0][3], 0, 0, 0);
                acc[1][2] = __builtin_amdgcn_mfma_f32_16x16x32_bf16(ca1, cb1, acc[1][2], 0, 0, 0);
                acc[1][3] = __builtin_amdgcn_mfma_f32_16x16x32_bf16(ca1, cb2, acc[1][3], 0, 0, 0);
            }
            ca0 = na0; ca1 = na1;
            cb0 = nb0; cb1 = nb1; cb2 = nb2;
        }
    }

    // ---- epilogue: LDS-transposed, coalesced stores (r24, byte-identical) ----
    for (int i2 = tid; i2 < Wn * JW; i2 += 256) sout[i2] = 0.0f;
    __syncthreads();                       // zeros visible

    if (y2ok) {
        const float scale = 1.0f / 256.0f;
#pragma unroll
        for (int a = 0; a < 2; ++a)
#pragma unroll
            for (int n = 0; n < 4; ++n)
#pragma unroll
                for (int r = 0; r < 4; ++r) {
                    int xp = (2 * h + a) * 16 + g * 4 + r;   // x' (C/D row)
                    int up = n * 16 + m16;                   // u' (C/D col)
                    int j  = up - xp + 10;
                    if ((unsigned)j < 21u)
                        sout[(2 * xp + p) * JW + j] = acc[a][n][r] * scale;
                }
    }
    __syncthreads();                       // scatter visible

    unsigned base0 = (unsigned)(((b * (GW * GW) + dyi * GW) * Hn + y) * Wn);
    constexpr unsigned PLANE = (unsigned)(Hn * Wn);
    for (int s = tid; s < GW * Wn; s += 256) {
        int j = s >> 7;
        int x = s & 127;
        out[base0 + (unsigned)j * PLANE + (unsigned)x] = sout[x * JW + j];
    }
}

// ---------------- fallback (r21, proven): used if ws too small ----------------
__device__ inline void lds_barrier() {
    asm volatile("s_waitcnt lgkmcnt(0)" ::: "memory");
    __builtin_amdgcn_s_barrier();
    __builtin_amdgcn_sched_barrier(0);
}

__global__ __launch_bounds__(256) void corr_mfma_fb(
    const float* __restrict__ in1, const float* __restrict__ in2,
    float* __restrict__ out)
{
    __shared__ unsigned lds[4][1024];
    int orig = blockIdx.x;
    int xcd  = orig & 7;
    int i    = orig >> 3;
    int yw   = i % 3;  int t = i / 3;
    int dyi  = t % 21; t /= 21;
    int sub  = t & 1;
    int par  = (t >> 1) & 1;
    int b    = t >> 2;
    int y    = 12 * xcd + par + 2 * (3 * sub + yw);
    int y2  = y + 2 * dyi - 20;
    bool y2ok = (y2 >= 0) && (y2 < Hn);

    int tid = threadIdx.x;
    int w   = tid >> 6;
    int l   = tid & 63;
    int p   = w >> 1;
    int h   = w & 1;
    int g   = l >> 4;
    int m16 = l & 15;

    const size_t chw = (size_t)Hn * Wn;
    const float* pA = in1 + ((size_t)b * Cn) * chw + (size_t)y * Wn;
    const float* pB = in2 + ((size_t)b * Cn) * chw + (size_t)(y2ok ? y2 : 0) * Wn;

    int tm = tid & 63;
    int tg = tid >> 6;
    const int loff = ((tm >> 4) * 4 + tg) * 64 + (tm & 15) * 4;

    f32x4 acc[2][4] = {};
    float ax[8], ay[8], bx[8], by[8];

    auto prefetch = [&](int chunk) {
        size_t base = (size_t)(chunk * KC + 8 * tg) * chw + 2 * tm;
#pragma unroll
        for (int k = 0; k < 8; ++k) {
            float2 tA = *(const float2*)(pA + base + (size_t)k * chw);
            float2 tB = *(const float2*)(pB + base + (size_t)k * chw);
            ax[k] = tA.x; ay[k] = tA.y;
            bx[k] = tB.x; by[k] = tB.y;
        }
        __builtin_amdgcn_sched_barrier(0);
    };
    auto writeout = [&]() {
#pragma unroll
        for (int k = 0; k < 8; ++k)
            asm volatile("" : "+v"(ax[k]), "+v"(ay[k]), "+v"(bx[k]), "+v"(by[k]));
        u32x4 ae, ao, be, bo;
#pragma unroll
        for (int ku = 0; ku < 4; ++ku) {
            ae[ku] = pack_bf16(ax[2 * ku], ax[2 * ku + 1]);
            ao[ku] = pack_bf16(ay[2 * ku], ay[2 * ku + 1]);
            be[ku] = pack_bf16(bx[2 * ku], bx[2 * ku + 1]);
            bo[ku] = pack_bf16(by[2 * ku], by[2 * ku + 1]);
        }
        *(u32x4*)&lds[0][loff] = ae;
        *(u32x4*)&lds[1][loff] = ao;
        *(u32x4*)&lds[2][loff] = be;
        *(u32x4*)&lds[3][loff] = bo;
    };
    auto compute = [&]() {
        const unsigned* Pa = &lds[p][0];
        const unsigned* Pb = &lds[2 + p][0];
        int fo = g * 64 + m16 * 4;
        bf16x8 A0  = *(const bf16x8*)(Pa + (2 * h + 0) * 256 + fo);
        bf16x8 A1  = *(const bf16x8*)(Pa + (2 * h + 1) * 256 + fo);
        bf16x8 Bf0 = *(const bf16x8*)(Pb + 0 * 256 + fo);
        bf16x8 Bf1 = *(const bf16x8*)(Pb + 1 * 256 + fo);
        bf16x8 Bf2 = *(const bf16x8*)(Pb + 2 * 256 + fo);
        bf16x8 Bf3 = *(const bf16x8*)(Pb + 3 * 256 + fo);
        acc[0][0] = __builtin_amdgcn_mfma_f32_16x16x32_bf16(A0, Bf0, acc[0][0], 0, 0, 0);
        acc[0][1] = __builtin_amdgcn_mfma_f32_16x16x32_bf16(A0, Bf1, acc[0][1], 0, 0, 0);
        acc[0][2] = __builtin_amdgcn_mfma_f32_16x16x32_bf16(A0, Bf2, acc[0][2], 0, 0, 0);
        acc[0][3] = __builtin_amdgcn_mfma_f32_16x16x32_bf16(A0, Bf3, acc[0][3], 0, 0, 0);
        acc[1][0] = __builtin_amdgcn_mfma_f32_16x16x32_bf16(A1, Bf0, acc[1][0], 0, 0, 0);
        acc[1][1] = __builtin_amdgcn_mfma_f32_16x16x32_bf16(A1, Bf1, acc[1][1], 0, 0, 0);
        acc[1][2] = __builtin_amdgcn_mfma_f32_16x16x32_bf16(A1, Bf2, acc[1][2], 0, 0, 0);
        acc[1][3] = __builtin_amdgcn_mfma_f32_16x16x32_bf16(A1, Bf3, acc[1][3], 0, 0, 0);
    };

    if (y2ok) {
        prefetch(0);
        for (int it = 0; it < NCH; ++it) {
            writeout();
            lds_barrier();
            if (it + 1 < NCH) prefetch(it + 1);
            compute();
            lds_barrier();
        }
    }

    __syncthreads();
    float* sout = (float*)&lds[0][0];
    for (int i2 = tid; i2 < Wn * JW; i2 += 256) sout[i2] = 0.0f;
    __syncthreads();
    if (y2ok) {
        const float scale = 1.0f / 256.0f;
#pragma unroll
        for (int a = 0; a < 2; ++a)
#pragma unroll
            for (int n = 0; n < 4; ++n)
#pragma unroll
                for (int r = 0; r < 4; ++r) {
                    int xp = (2 * h + a) * 16 + g * 4 + r;
                    int up = n * 16 + m16;
                    int j  = up - xp + 10;
                    if ((unsigned)j < 21u)
                        sout[(2 * xp + p) * JW + j] = acc[a][n][r] * scale;
                }
    }
    __syncthreads();
    unsigned base0 = (unsigned)(((b * (GW * GW) + dyi * GW) * Hn + y) * Wn);
    constexpr unsigned PLANE = (unsigned)(Hn * Wn);
    for (int s = tid; s < GW * Wn; s += 256) {
        int j = s >> 7;
        int x = s & 127;
        out[base0 + (unsigned)j * PLANE + (unsigned)x] = sout[x * JW + j];
    }
}

extern "C" void kernel_launch(void* const* d_in, const int* in_sizes, int n_in,
                              void* d_out, int out_size, void* d_ws, size_t ws_size,
                              hipStream_t stream) {
    const float* in1 = (const float*)d_in[0];
    const float* in2 = (const float*)d_in[1];
    float* out = (float*)d_out;
    size_t need = 2 * TELEMS * sizeof(unsigned);   // 100,663,296 B
    if (ws_size >= need) {
        unsigned* T = (unsigned*)d_ws;
        prepack<<<2 * Bn * Hn * NCH, 256, 0, stream>>>(in1, in2, T);
        corr_frag<<<NWG, 256, 0, stream>>>(T, T + TELEMS, out);
    } else {
        corr_mfma_fb<<<NWG, 256, 0, stream>>>(in1, in2, out);
    }
}